// Round 1
// baseline (828.987 us; speedup 1.0000x reference)
//
#include <hip/hip_runtime.h>
#include <hip/hip_bf16.h>
#include <math.h>

#define HEADS 4
#define HID 48
#define FDIM 192   // HEADS*HID
#define NEG_SLOPE 0.2f

// ---------------------------------------------------------------------------
// Detect whether edge_index buffer is int64 (odd 32-bit words all zero) or int32.
__global__ void detect_kernel(const int* __restrict__ ei, int* __restrict__ flag) {
    if (threadIdx.x == 0) {
        int is64 = 1;
        for (int i = 1; i < 64; i += 2) {
            if (ei[i] != 0) { is64 = 0; break; }
        }
        *flag = is64;
    }
}

// ---------------------------------------------------------------------------
// Histogram of destination nodes (including self-loops e in [E, E+N)).
__global__ void hist_kernel(const int* __restrict__ ei, const int* __restrict__ flag,
                            int* __restrict__ deg, int E, int E2) {
    int is64 = *flag;
    for (int e = blockIdx.x * blockDim.x + threadIdx.x; e < E2;
         e += gridDim.x * blockDim.x) {
        int d;
        if (e < E) d = is64 ? ei[2 * (E + e)] : ei[E + e];
        else       d = e - E;
        atomicAdd(&deg[d], 1);
    }
}

// ---------------------------------------------------------------------------
// Single-block exclusive scan of deg -> rowptr (N up to ~50k, 1024 threads).
__global__ void scan_kernel(const int* __restrict__ deg, int* __restrict__ rowptr, int N) {
    __shared__ int sm[1024];
    __shared__ int running;
    if (threadIdx.x == 0) { running = 0; rowptr[0] = 0; }
    __syncthreads();
    for (int base = 0; base < N; base += 1024) {
        int i = base + (int)threadIdx.x;
        int v = (i < N) ? deg[i] : 0;
        sm[threadIdx.x] = v;
        __syncthreads();
        for (int off = 1; off < 1024; off <<= 1) {
            int t = 0;
            if ((int)threadIdx.x >= off) t = sm[threadIdx.x - off];
            __syncthreads();
            sm[threadIdx.x] += t;
            __syncthreads();
        }
        if (i < N) rowptr[i + 1] = running + sm[threadIdx.x];
        __syncthreads();
        if (threadIdx.x == 0) running += sm[1023];
        __syncthreads();
    }
}

// ---------------------------------------------------------------------------
// Scatter edges into CSR order (sorted by dst). cursor must be zeroed.
__global__ void scatter_kernel(const int* __restrict__ ei, const int* __restrict__ flag,
                               const int* __restrict__ rowptr, int* __restrict__ cursor,
                               int* __restrict__ srcs, int E, int E2) {
    int is64 = *flag;
    for (int e = blockIdx.x * blockDim.x + threadIdx.x; e < E2;
         e += gridDim.x * blockDim.x) {
        int s, d;
        if (e < E) {
            if (is64) { s = ei[2 * e]; d = ei[2 * (E + e)]; }
            else      { s = ei[e];     d = ei[E + e]; }
        } else {
            s = d = e - E;
        }
        int pos = rowptr[d] + atomicAdd(&cursor[d], 1);
        srcs[pos] = s;
    }
}

// ---------------------------------------------------------------------------
// Dual GEMM: xl = xin@Wl + bl, xr = xin@Wr + br.  One block (192 thr) per node.
__global__ void gemm2_kernel(const float* __restrict__ xin, int din,
                             const float* __restrict__ Wl, const float* __restrict__ bl,
                             const float* __restrict__ Wr, const float* __restrict__ br,
                             float* __restrict__ xl, float* __restrict__ xr, int N) {
    int n = blockIdx.x;
    if (n >= N) return;
    int j = threadIdx.x;  // 0..191
    const float* xrow = xin + (size_t)n * din;
    float aL = bl[j];
    float aR = br[j];
    for (int k = 0; k < din; ++k) {
        float xv = xrow[k];
        aL = fmaf(xv, Wl[k * FDIM + j], aL);
        aR = fmaf(xv, Wr[k * FDIM + j], aR);
    }
    xl[(size_t)n * FDIM + j] = aL;
    xr[(size_t)n * FDIM + j] = aR;
}

// ---------------------------------------------------------------------------
// Merged GATv2 layer: one wave (64 lanes) per destination node.
// lane -> head h = lane>>4, channel base cl = lane&15; owns channels cl, cl+16, cl+32.
// Online-softmax (flash style) over incoming edges; epilogue = head-mean + bias + ELU.
// Final layer additionally fuses head MLP + ReLU into out[n].
__global__ __launch_bounds__(256) void gat_layer_kernel(
    const float* __restrict__ xl, const float* __restrict__ xr,
    const float* __restrict__ att, const float* __restrict__ bias,
    const int* __restrict__ rowptr, const int* __restrict__ srcs,
    float* __restrict__ xout,                       // [N,48] (non-final)
    float* __restrict__ out,                        // [N]    (final)
    const float* __restrict__ head_w, const float* __restrict__ head_b,
    int N, int final_flag) {
    int wave = (int)((blockIdx.x * blockDim.x + threadIdx.x) >> 6);
    int lane = (int)(threadIdx.x & 63);
    if (wave >= N) return;
    int n  = wave;
    int h  = lane >> 4;
    int cl = lane & 15;
    int j0 = h * HID + cl;          // flat index into [4*48]

    float a0 = att[j0], a1 = att[j0 + 16], a2 = att[j0 + 32];
    const float* xrp = xr + (size_t)n * FDIM;
    float r0 = xrp[j0], r1 = xrp[j0 + 16], r2 = xrp[j0 + 32];

    float m = -INFINITY, denom = 0.f;
    float acc0 = 0.f, acc1 = 0.f, acc2 = 0.f;

    int e0 = rowptr[n], e1 = rowptr[n + 1];
    for (int e = e0; e < e1; ++e) {
        int s = srcs[e];
        const float* xlp = xl + (size_t)s * FDIM;
        float l0 = xlp[j0], l1 = xlp[j0 + 16], l2 = xlp[j0 + 32];
        float t0 = l0 + r0; t0 = (t0 > 0.f) ? t0 : NEG_SLOPE * t0;
        float t1 = l1 + r1; t1 = (t1 > 0.f) ? t1 : NEG_SLOPE * t1;
        float t2 = l2 + r2; t2 = (t2 > 0.f) ? t2 : NEG_SLOPE * t2;
        float part = t0 * a0 + t1 * a1 + t2 * a2;
        part += __shfl_xor(part, 1);
        part += __shfl_xor(part, 2);
        part += __shfl_xor(part, 4);
        part += __shfl_xor(part, 8);     // all 16 lanes of head group hold score
        float nm    = fmaxf(m, part);
        float scale = __expf(m - nm);    // m=-inf first iter -> 0
        float p     = __expf(part - nm);
        denom = denom * scale + p;
        acc0  = acc0 * scale + p * l0;
        acc1  = acc1 * scale + p * l1;
        acc2  = acc2 * scale + p * l2;
        m = nm;
    }

    float inv = 1.0f / (denom + 1e-16f);
    float o0 = acc0 * inv, o1 = acc1 * inv, o2 = acc2 * inv;
    // mean over heads: sum across the 4 head groups
    o0 += __shfl_xor(o0, 16); o0 += __shfl_xor(o0, 32);
    o1 += __shfl_xor(o1, 16); o1 += __shfl_xor(o1, 32);
    o2 += __shfl_xor(o2, 16); o2 += __shfl_xor(o2, 32);
    o0 = 0.25f * o0 + bias[cl];
    o1 = 0.25f * o1 + bias[cl + 16];
    o2 = 0.25f * o2 + bias[cl + 32];
    // ELU
    o0 = (o0 > 0.f) ? o0 : expm1f(o0);
    o1 = (o1 > 0.f) ? o1 : expm1f(o1);
    o2 = (o2 > 0.f) ? o2 : expm1f(o2);

    if (!final_flag) {
        if (h == 0) {
            float* xo = xout + (size_t)n * HID;
            xo[cl] = o0; xo[cl + 16] = o1; xo[cl + 32] = o2;
        }
    } else {
        float part = o0 * head_w[cl] + o1 * head_w[cl + 16] + o2 * head_w[cl + 32];
        part += __shfl_xor(part, 1);
        part += __shfl_xor(part, 2);
        part += __shfl_xor(part, 4);
        part += __shfl_xor(part, 8);
        if (lane == 0) {
            float v = part + head_b[0];
            out[n] = (v > 0.f) ? v : 0.f;
        }
    }
}

// ---------------------------------------------------------------------------
extern "C" void kernel_launch(void* const* d_in, const int* in_sizes, int n_in,
                              void* d_out, int out_size, void* d_ws, size_t ws_size,
                              hipStream_t stream) {
    const float* x0 = (const float*)d_in[0];
    const int*   ei = (const int*)d_in[1];

    const int N  = in_sizes[0] / 3;        // 50000
    const int E  = in_sizes[1] / 2;        // 800000
    const int E2 = E + N;                  // edges incl. self-loops

    // layer params: base = 2 + 6*li : Wl, bl, Wr, br, att, bias
    const float* Wl[3];  const float* bl[3];
    const float* Wr[3];  const float* br[3];
    const float* att[3]; const float* bias[3];
    for (int li = 0; li < 3; ++li) {
        int b = 2 + 6 * li;
        Wl[li]   = (const float*)d_in[b + 0];
        bl[li]   = (const float*)d_in[b + 1];
        Wr[li]   = (const float*)d_in[b + 2];
        br[li]   = (const float*)d_in[b + 3];
        att[li]  = (const float*)d_in[b + 4];
        bias[li] = (const float*)d_in[b + 5];
    }
    const float* head_w = (const float*)d_in[20];
    const float* head_b = (const float*)d_in[21];
    float* out = (float*)d_out;

    // ---- workspace carve-up (256B aligned) ----
    size_t off = 0;
    auto alloc = [&](size_t bytes) -> void* {
        void* p = (char*)d_ws + off;
        off = (off + bytes + 255) & ~(size_t)255;
        return p;
    };
    int*   flag   = (int*)alloc(sizeof(int));
    int*   deg    = (int*)alloc((size_t)N * sizeof(int));        // reused as cursor
    int*   rowptr = (int*)alloc((size_t)(N + 1) * sizeof(int));
    int*   srcs   = (int*)alloc((size_t)E2 * sizeof(int));
    float* xlb    = (float*)alloc((size_t)N * FDIM * sizeof(float));
    float* xrb    = (float*)alloc((size_t)N * FDIM * sizeof(float));
    float* xbuf   = (float*)alloc((size_t)N * HID * sizeof(float));
    (void)ws_size;

    // ---- build CSR (layer-invariant) ----
    detect_kernel<<<1, 64, 0, stream>>>(ei, flag);
    hipMemsetAsync(deg, 0, (size_t)N * sizeof(int), stream);
    {
        int blocks = 2048;
        hist_kernel<<<blocks, 256, 0, stream>>>(ei, flag, deg, E, E2);
    }
    scan_kernel<<<1, 1024, 0, stream>>>(deg, rowptr, N);
    hipMemsetAsync(deg, 0, (size_t)N * sizeof(int), stream);
    {
        int blocks = 2048;
        scatter_kernel<<<blocks, 256, 0, stream>>>(ei, flag, rowptr, deg, srcs, E, E2);
    }

    const int waves_per_block = 4;  // 256 threads
    int gat_blocks = (N + waves_per_block - 1) / waves_per_block;

    // ---- layer 0 (din=3) ----
    gemm2_kernel<<<N, FDIM, 0, stream>>>(x0, 3, Wl[0], bl[0], Wr[0], br[0], xlb, xrb, N);
    gat_layer_kernel<<<gat_blocks, 256, 0, stream>>>(xlb, xrb, att[0], bias[0],
        rowptr, srcs, xbuf, nullptr, nullptr, nullptr, N, 0);

    // ---- layer 1 (din=48) ----
    gemm2_kernel<<<N, FDIM, 0, stream>>>(xbuf, HID, Wl[1], bl[1], Wr[1], br[1], xlb, xrb, N);
    gat_layer_kernel<<<gat_blocks, 256, 0, stream>>>(xlb, xrb, att[1], bias[1],
        rowptr, srcs, xbuf, nullptr, nullptr, nullptr, N, 0);

    // ---- layer 2 (din=48) + fused head MLP + ReLU ----
    gemm2_kernel<<<N, FDIM, 0, stream>>>(xbuf, HID, Wl[2], bl[2], Wr[2], br[2], xlb, xrb, N);
    gat_layer_kernel<<<gat_blocks, 256, 0, stream>>>(xlb, xrb, att[2], bias[2],
        rowptr, srcs, nullptr, out, head_w, head_b, N, 1);

    (void)n_in; (void)out_size;
}

// Round 3
// 657.178 us; speedup vs baseline: 1.2614x; 1.2614x over previous
//
#include <hip/hip_runtime.h>
#include <hip/hip_bf16.h>
#include <math.h>

#define HEADS 4
#define HID 48
#define FDIM 192   // HEADS*HID
#define NEG_SLOPE 0.2f

typedef float f4 __attribute__((ext_vector_type(4)));

// ---------------------------------------------------------------------------
// Detect whether edge_index buffer is int64 (odd 32-bit words all zero) or int32.
__global__ void detect_kernel(const int* __restrict__ ei, int* __restrict__ flag) {
    if (threadIdx.x == 0) {
        int is64 = 1;
        for (int i = 1; i < 64; i += 2) {
            if (ei[i] != 0) { is64 = 0; break; }
        }
        *flag = is64;
    }
}

// ---------------------------------------------------------------------------
// Histogram of destination nodes (including self-loops e in [E, E+N)).
__global__ void hist_kernel(const int* __restrict__ ei, const int* __restrict__ flag,
                            int* __restrict__ deg, int E, int E2) {
    int is64 = *flag;
    for (int e = blockIdx.x * blockDim.x + threadIdx.x; e < E2;
         e += gridDim.x * blockDim.x) {
        int d;
        if (e < E) d = is64 ? ei[2 * (E + e)] : ei[E + e];
        else       d = e - E;
        atomicAdd(&deg[d], 1);
    }
}

// ---------------------------------------------------------------------------
// Single-block exclusive scan of deg -> rowptr (N up to ~50k, 1024 threads).
__global__ void scan_kernel(const int* __restrict__ deg, int* __restrict__ rowptr, int N) {
    __shared__ int sm[1024];
    __shared__ int running;
    if (threadIdx.x == 0) { running = 0; rowptr[0] = 0; }
    __syncthreads();
    for (int base = 0; base < N; base += 1024) {
        int i = base + (int)threadIdx.x;
        int v = (i < N) ? deg[i] : 0;
        sm[threadIdx.x] = v;
        __syncthreads();
        for (int off = 1; off < 1024; off <<= 1) {
            int t = 0;
            if ((int)threadIdx.x >= off) t = sm[threadIdx.x - off];
            __syncthreads();
            sm[threadIdx.x] += t;
            __syncthreads();
        }
        if (i < N) rowptr[i + 1] = running + sm[threadIdx.x];
        __syncthreads();
        if (threadIdx.x == 0) running += sm[1023];
        __syncthreads();
    }
}

// ---------------------------------------------------------------------------
// Scatter edges into CSR order (sorted by dst). cursor must be zeroed.
__global__ void scatter_kernel(const int* __restrict__ ei, const int* __restrict__ flag,
                               const int* __restrict__ rowptr, int* __restrict__ cursor,
                               int* __restrict__ srcs, int E, int E2) {
    int is64 = *flag;
    for (int e = blockIdx.x * blockDim.x + threadIdx.x; e < E2;
         e += gridDim.x * blockDim.x) {
        int s, d;
        if (e < E) {
            if (is64) { s = ei[2 * e]; d = ei[2 * (E + e)]; }
            else      { s = ei[e];     d = ei[E + e]; }
        } else {
            s = d = e - E;
        }
        int pos = rowptr[d] + atomicAdd(&cursor[d], 1);
        srcs[pos] = s;
    }
}

// ---------------------------------------------------------------------------
// Dual GEMM, register-tiled: xl = xin@Wl + bl, xr = xin@Wr + br.
// Block = 192 threads = 4 node-groups x 48 column-groups; 16 nodes/block.
// Thread owns 4 output columns (f4 vector) x 4 nodes for BOTH L and R.
template<int DIN>
__global__ __launch_bounds__(192) void gemm2t_kernel(
    const float* __restrict__ xin,
    const float* __restrict__ Wl, const float* __restrict__ bl,
    const float* __restrict__ Wr, const float* __restrict__ br,
    float* __restrict__ xl, float* __restrict__ xr, int N) {
    int t  = (int)threadIdx.x;
    int cg = t % 48;           // column group -> cols c0..c0+3
    int ng = t / 48;           // node group 0..3
    int c0 = cg * 4;
    int n0 = blockIdx.x * 16 + ng * 4;
    if (n0 >= N) return;

    f4 bLv = *(const f4*)&bl[c0];
    f4 bRv = *(const f4*)&br[c0];
    f4 accL[4], accR[4];
    #pragma unroll
    for (int i = 0; i < 4; ++i) { accL[i] = bLv; accR[i] = bRv; }

    if (n0 + 3 < N) {
        if (DIN == 3) {
            float xv[4][3];
            #pragma unroll
            for (int i = 0; i < 4; ++i) {
                const float* xp = xin + (size_t)(n0 + i) * 3;
                xv[i][0] = xp[0]; xv[i][1] = xp[1]; xv[i][2] = xp[2];
            }
            #pragma unroll
            for (int k = 0; k < 3; ++k) {
                f4 wl4 = *(const f4*)&Wl[k * FDIM + c0];
                f4 wr4 = *(const f4*)&Wr[k * FDIM + c0];
                #pragma unroll
                for (int i = 0; i < 4; ++i) {
                    float xs = xv[i][k];
                    accL[i] += xs * wl4;
                    accR[i] += xs * wr4;
                }
            }
        } else {
            #pragma unroll
            for (int kk = 0; kk < DIN; kk += 8) {
                float xv[4][8];
                #pragma unroll
                for (int i = 0; i < 4; ++i) {
                    const float* xp = xin + (size_t)(n0 + i) * DIN + kk;
                    f4 xa = *(const f4*)xp;
                    f4 xb = *(const f4*)(xp + 4);
                    #pragma unroll
                    for (int q = 0; q < 4; ++q) { xv[i][q] = xa[q]; xv[i][4 + q] = xb[q]; }
                }
                #pragma unroll
                for (int k = 0; k < 8; ++k) {
                    f4 wl4 = *(const f4*)&Wl[(kk + k) * FDIM + c0];
                    f4 wr4 = *(const f4*)&Wr[(kk + k) * FDIM + c0];
                    #pragma unroll
                    for (int i = 0; i < 4; ++i) {
                        float xs = xv[i][k];
                        accL[i] += xs * wl4;
                        accR[i] += xs * wr4;
                    }
                }
            }
        }
        #pragma unroll
        for (int i = 0; i < 4; ++i) {
            *(f4*)&xl[(size_t)(n0 + i) * FDIM + c0] = accL[i];
            *(f4*)&xr[(size_t)(n0 + i) * FDIM + c0] = accR[i];
        }
    } else {
        // tail (not taken for N % 16 == 0, kept for correctness)
        for (int i = 0; i < 4; ++i) {
            int n = n0 + i;
            if (n >= N) break;
            f4 aL = bLv;
            f4 aR = bRv;
            for (int k = 0; k < DIN; ++k) {
                float xs = xin[(size_t)n * DIN + k];
                f4 wl4 = *(const f4*)&Wl[k * FDIM + c0];
                f4 wr4 = *(const f4*)&Wr[k * FDIM + c0];
                aL += xs * wl4;
                aR += xs * wr4;
            }
            *(f4*)&xl[(size_t)n * FDIM + c0] = aL;
            *(f4*)&xr[(size_t)n * FDIM + c0] = aR;
        }
    }
}

// ---------------------------------------------------------------------------
// Merged GATv2 layer: one wave (64 lanes) per destination node.
// lane -> head h = lane>>4, channel base cl = lane&15; owns channels cl, cl+16, cl+32.
// Online-softmax (flash style) over incoming edges; epilogue = head-mean + bias + ELU.
// Final layer additionally fuses head MLP + ReLU into out[n].
__global__ __launch_bounds__(256) void gat_layer_kernel(
    const float* __restrict__ xl, const float* __restrict__ xr,
    const float* __restrict__ att, const float* __restrict__ bias,
    const int* __restrict__ rowptr, const int* __restrict__ srcs,
    float* __restrict__ xout,                       // [N,48] (non-final)
    float* __restrict__ out,                        // [N]    (final)
    const float* __restrict__ head_w, const float* __restrict__ head_b,
    int N, int final_flag) {
    int wave = (int)((blockIdx.x * blockDim.x + threadIdx.x) >> 6);
    int lane = (int)(threadIdx.x & 63);
    if (wave >= N) return;
    int n  = wave;
    int h  = lane >> 4;
    int cl = lane & 15;
    int j0 = h * HID + cl;          // flat index into [4*48]

    float a0 = att[j0], a1 = att[j0 + 16], a2 = att[j0 + 32];
    const float* xrp = xr + (size_t)n * FDIM;
    float r0 = xrp[j0], r1 = xrp[j0 + 16], r2 = xrp[j0 + 32];

    float m = -INFINITY, denom = 0.f;
    float acc0 = 0.f, acc1 = 0.f, acc2 = 0.f;

    int e0 = rowptr[n], e1 = rowptr[n + 1];
    for (int e = e0; e < e1; ++e) {
        int s = srcs[e];
        const float* xlp = xl + (size_t)s * FDIM;
        float l0 = xlp[j0], l1 = xlp[j0 + 16], l2 = xlp[j0 + 32];
        float t0 = l0 + r0; t0 = (t0 > 0.f) ? t0 : NEG_SLOPE * t0;
        float t1 = l1 + r1; t1 = (t1 > 0.f) ? t1 : NEG_SLOPE * t1;
        float t2 = l2 + r2; t2 = (t2 > 0.f) ? t2 : NEG_SLOPE * t2;
        float part = t0 * a0 + t1 * a1 + t2 * a2;
        part += __shfl_xor(part, 1);
        part += __shfl_xor(part, 2);
        part += __shfl_xor(part, 4);
        part += __shfl_xor(part, 8);     // all 16 lanes of head group hold score
        float nm    = fmaxf(m, part);
        float scale = __expf(m - nm);    // m=-inf first iter -> 0
        float p     = __expf(part - nm);
        denom = denom * scale + p;
        acc0  = acc0 * scale + p * l0;
        acc1  = acc1 * scale + p * l1;
        acc2  = acc2 * scale + p * l2;
        m = nm;
    }

    float inv = 1.0f / (denom + 1e-16f);
    float o0 = acc0 * inv, o1 = acc1 * inv, o2 = acc2 * inv;
    // mean over heads: sum across the 4 head groups
    o0 += __shfl_xor(o0, 16); o0 += __shfl_xor(o0, 32);
    o1 += __shfl_xor(o1, 16); o1 += __shfl_xor(o1, 32);
    o2 += __shfl_xor(o2, 16); o2 += __shfl_xor(o2, 32);
    o0 = 0.25f * o0 + bias[cl];
    o1 = 0.25f * o1 + bias[cl + 16];
    o2 = 0.25f * o2 + bias[cl + 32];
    // ELU
    o0 = (o0 > 0.f) ? o0 : expm1f(o0);
    o1 = (o1 > 0.f) ? o1 : expm1f(o1);
    o2 = (o2 > 0.f) ? o2 : expm1f(o2);

    if (!final_flag) {
        if (h == 0) {
            float* xo = xout + (size_t)n * HID;
            xo[cl] = o0; xo[cl + 16] = o1; xo[cl + 32] = o2;
        }
    } else {
        float part = o0 * head_w[cl] + o1 * head_w[cl + 16] + o2 * head_w[cl + 32];
        part += __shfl_xor(part, 1);
        part += __shfl_xor(part, 2);
        part += __shfl_xor(part, 4);
        part += __shfl_xor(part, 8);
        if (lane == 0) {
            float v = part + head_b[0];
            out[n] = (v > 0.f) ? v : 0.f;
        }
    }
}

// ---------------------------------------------------------------------------
extern "C" void kernel_launch(void* const* d_in, const int* in_sizes, int n_in,
                              void* d_out, int out_size, void* d_ws, size_t ws_size,
                              hipStream_t stream) {
    const float* x0 = (const float*)d_in[0];
    const int*   ei = (const int*)d_in[1];

    const int N  = in_sizes[0] / 3;        // 50000
    const int E  = in_sizes[1] / 2;        // 800000
    const int E2 = E + N;                  // edges incl. self-loops

    // layer params: base = 2 + 6*li : Wl, bl, Wr, br, att, bias
    const float* Wl[3];  const float* bl[3];
    const float* Wr[3];  const float* br[3];
    const float* att[3]; const float* bias[3];
    for (int li = 0; li < 3; ++li) {
        int b = 2 + 6 * li;
        Wl[li]   = (const float*)d_in[b + 0];
        bl[li]   = (const float*)d_in[b + 1];
        Wr[li]   = (const float*)d_in[b + 2];
        br[li]   = (const float*)d_in[b + 3];
        att[li]  = (const float*)d_in[b + 4];
        bias[li] = (const float*)d_in[b + 5];
    }
    const float* head_w = (const float*)d_in[20];
    const float* head_b = (const float*)d_in[21];
    float* out = (float*)d_out;

    // ---- workspace carve-up (256B aligned) ----
    size_t off = 0;
    auto alloc = [&](size_t bytes) -> void* {
        void* p = (char*)d_ws + off;
        off = (off + bytes + 255) & ~(size_t)255;
        return p;
    };
    int*   flag   = (int*)alloc(sizeof(int));
    int*   deg    = (int*)alloc((size_t)N * sizeof(int));        // reused as cursor
    int*   rowptr = (int*)alloc((size_t)(N + 1) * sizeof(int));
    int*   srcs   = (int*)alloc((size_t)E2 * sizeof(int));
    float* xlb    = (float*)alloc((size_t)N * FDIM * sizeof(float));
    float* xrb    = (float*)alloc((size_t)N * FDIM * sizeof(float));
    float* xbuf   = (float*)alloc((size_t)N * HID * sizeof(float));
    (void)ws_size;

    // ---- build CSR (layer-invariant) ----
    detect_kernel<<<1, 64, 0, stream>>>(ei, flag);
    (void)hipMemsetAsync(deg, 0, (size_t)N * sizeof(int), stream);
    hist_kernel<<<2048, 256, 0, stream>>>(ei, flag, deg, E, E2);
    scan_kernel<<<1, 1024, 0, stream>>>(deg, rowptr, N);
    (void)hipMemsetAsync(deg, 0, (size_t)N * sizeof(int), stream);
    scatter_kernel<<<2048, 256, 0, stream>>>(ei, flag, rowptr, deg, srcs, E, E2);

    const int waves_per_block = 4;  // 256 threads
    int gat_blocks = (N + waves_per_block - 1) / waves_per_block;
    int gemm_blocks = (N + 15) / 16;

    // ---- layer 0 (din=3) ----
    gemm2t_kernel<3><<<gemm_blocks, 192, 0, stream>>>(x0, Wl[0], bl[0], Wr[0], br[0], xlb, xrb, N);
    gat_layer_kernel<<<gat_blocks, 256, 0, stream>>>(xlb, xrb, att[0], bias[0],
        rowptr, srcs, xbuf, nullptr, nullptr, nullptr, N, 0);

    // ---- layer 1 (din=48) ----
    gemm2t_kernel<HID><<<gemm_blocks, 192, 0, stream>>>(xbuf, Wl[1], bl[1], Wr[1], br[1], xlb, xrb, N);
    gat_layer_kernel<<<gat_blocks, 256, 0, stream>>>(xlb, xrb, att[1], bias[1],
        rowptr, srcs, xbuf, nullptr, nullptr, nullptr, N, 0);

    // ---- layer 2 (din=48) + fused head MLP + ReLU ----
    gemm2t_kernel<HID><<<gemm_blocks, 192, 0, stream>>>(xbuf, Wl[2], bl[2], Wr[2], br[2], xlb, xrb, N);
    gat_layer_kernel<<<gat_blocks, 256, 0, stream>>>(xlb, xrb, att[2], bias[2],
        rowptr, srcs, nullptr, out, head_w, head_b, N, 1);

    (void)n_in; (void)out_size;
}

// Round 4
// 497.158 us; speedup vs baseline: 1.6675x; 1.3219x over previous
//
#include <hip/hip_runtime.h>
#include <hip/hip_bf16.h>
#include <math.h>

#define HEADS 4
#define HID 48
#define FDIM 192   // HEADS*HID
#define NEG_SLOPE 0.2f

typedef float f4 __attribute__((ext_vector_type(4)));

// ---------------------------------------------------------------------------
// DPP helpers: 16-lane sum reduction entirely on the VALU pipe.
// quad_perm [1,0,3,2] = 0xB1 (xor1), [2,3,0,1] = 0x4E (xor2),
// row_ror:4 = 0x124, row_ror:8 = 0x128 (rotation within the 16-lane row).
template<int CTRL>
__device__ __forceinline__ float dpp_add(float v) {
    int t = __builtin_amdgcn_update_dpp(0, __float_as_int(v), CTRL, 0xF, 0xF, true);
    return v + __int_as_float(t);
}
__device__ __forceinline__ float red16(float v) {
    v = dpp_add<0xB1>(v);
    v = dpp_add<0x4E>(v);
    v = dpp_add<0x124>(v);
    v = dpp_add<0x128>(v);
    return v;   // all 16 lanes of the row-group hold the full sum
}

// ---------------------------------------------------------------------------
// Detect int64 vs int32 edge_index: odd 32-bit words all zero -> int64.
__global__ void detect_kernel(const int* __restrict__ ei, int* __restrict__ flag) {
    int l = (int)threadIdx.x;                 // 64 lanes check 64 odd words
    int v = ei[2 * l + 1];
    unsigned long long b = __ballot(v != 0);
    if (l == 0) *flag = (b == 0ULL) ? 1 : 0;
}

// ---------------------------------------------------------------------------
// Histogram of destination nodes (including self-loops e in [E, E+N)).
__global__ void hist_kernel(const int* __restrict__ ei, const int* __restrict__ flag,
                            int* __restrict__ deg, int E, int E2) {
    int is64 = *flag;
    for (int e = blockIdx.x * blockDim.x + threadIdx.x; e < E2;
         e += gridDim.x * blockDim.x) {
        int d;
        if (e < E) d = is64 ? ei[2 * (E + e)] : ei[E + e];
        else       d = e - E;
        atomicAdd(&deg[d], 1);
    }
}

// ---------------------------------------------------------------------------
// Hierarchical scan: (A) per-block inclusive scan + block sums,
// (B) single-block exclusive scan of block sums, (C) add offsets -> rowptr.
__global__ void scan_local_kernel(const int* __restrict__ deg, int* __restrict__ incl,
                                  int* __restrict__ bsum, int N) {
    __shared__ int sm[256];
    int i = blockIdx.x * 256 + threadIdx.x;
    int v = (i < N) ? deg[i] : 0;
    sm[threadIdx.x] = v;
    __syncthreads();
    #pragma unroll
    for (int off = 1; off < 256; off <<= 1) {
        int t = ((int)threadIdx.x >= off) ? sm[threadIdx.x - off] : 0;
        __syncthreads();
        sm[threadIdx.x] += t;
        __syncthreads();
    }
    if (i < N) incl[i] = sm[threadIdx.x];
    if (threadIdx.x == 255) bsum[blockIdx.x] = sm[255];
}

__global__ void scan_bsum_kernel(int* __restrict__ bsum, int nb) {
    __shared__ int sm[256];
    __shared__ int running;
    if (threadIdx.x == 0) running = 0;
    __syncthreads();
    for (int base = 0; base < nb; base += 256) {
        int i = base + (int)threadIdx.x;
        int v = (i < nb) ? bsum[i] : 0;
        sm[threadIdx.x] = v;
        __syncthreads();
        #pragma unroll
        for (int off = 1; off < 256; off <<= 1) {
            int t = ((int)threadIdx.x >= off) ? sm[threadIdx.x - off] : 0;
            __syncthreads();
            sm[threadIdx.x] += t;
            __syncthreads();
        }
        if (i < nb) bsum[i] = running + sm[threadIdx.x] - v;   // exclusive
        __syncthreads();
        if (threadIdx.x == 0) running += sm[255];
        __syncthreads();
    }
}

__global__ void scan_final_kernel(const int* __restrict__ incl, const int* __restrict__ bsum,
                                  int* __restrict__ rowptr, int N) {
    int i = blockIdx.x * 256 + threadIdx.x;
    if (i < N) rowptr[i + 1] = incl[i] + bsum[blockIdx.x];
    if (i == 0) rowptr[0] = 0;
}

// ---------------------------------------------------------------------------
// Scatter edges into CSR order (sorted by dst). cursor must be zeroed.
__global__ void scatter_kernel(const int* __restrict__ ei, const int* __restrict__ flag,
                               const int* __restrict__ rowptr, int* __restrict__ cursor,
                               int* __restrict__ srcs, int E, int E2) {
    int is64 = *flag;
    for (int e = blockIdx.x * blockDim.x + threadIdx.x; e < E2;
         e += gridDim.x * blockDim.x) {
        int s, d;
        if (e < E) {
            if (is64) { s = ei[2 * e]; d = ei[2 * (E + e)]; }
            else      { s = ei[e];     d = ei[E + e]; }
        } else {
            s = d = e - E;
        }
        int pos = rowptr[d] + atomicAdd(&cursor[d], 1);
        srcs[pos] = s;
    }
}

// ---------------------------------------------------------------------------
// Dual GEMM, register-tiled: xl = xin@Wl + bl, xr = xin@Wr + br.
template<int DIN>
__global__ __launch_bounds__(192) void gemm2t_kernel(
    const float* __restrict__ xin,
    const float* __restrict__ Wl, const float* __restrict__ bl,
    const float* __restrict__ Wr, const float* __restrict__ br,
    float* __restrict__ xl, float* __restrict__ xr, int N) {
    int t  = (int)threadIdx.x;
    int cg = t % 48;           // column group -> cols c0..c0+3
    int ng = t / 48;           // node group 0..3
    int c0 = cg * 4;
    int n0 = blockIdx.x * 16 + ng * 4;
    if (n0 >= N) return;

    f4 bLv = *(const f4*)&bl[c0];
    f4 bRv = *(const f4*)&br[c0];
    f4 accL[4], accR[4];
    #pragma unroll
    for (int i = 0; i < 4; ++i) { accL[i] = bLv; accR[i] = bRv; }

    if (n0 + 3 < N) {
        if (DIN == 3) {
            float xv[4][3];
            #pragma unroll
            for (int i = 0; i < 4; ++i) {
                const float* xp = xin + (size_t)(n0 + i) * 3;
                xv[i][0] = xp[0]; xv[i][1] = xp[1]; xv[i][2] = xp[2];
            }
            #pragma unroll
            for (int k = 0; k < 3; ++k) {
                f4 wl4 = *(const f4*)&Wl[k * FDIM + c0];
                f4 wr4 = *(const f4*)&Wr[k * FDIM + c0];
                #pragma unroll
                for (int i = 0; i < 4; ++i) {
                    float xs = xv[i][k];
                    accL[i] += xs * wl4;
                    accR[i] += xs * wr4;
                }
            }
        } else {
            #pragma unroll
            for (int kk = 0; kk < DIN; kk += 8) {
                float xv[4][8];
                #pragma unroll
                for (int i = 0; i < 4; ++i) {
                    const float* xp = xin + (size_t)(n0 + i) * DIN + kk;
                    f4 xa = *(const f4*)xp;
                    f4 xb = *(const f4*)(xp + 4);
                    #pragma unroll
                    for (int q = 0; q < 4; ++q) { xv[i][q] = xa[q]; xv[i][4 + q] = xb[q]; }
                }
                #pragma unroll
                for (int k = 0; k < 8; ++k) {
                    f4 wl4 = *(const f4*)&Wl[(kk + k) * FDIM + c0];
                    f4 wr4 = *(const f4*)&Wr[(kk + k) * FDIM + c0];
                    #pragma unroll
                    for (int i = 0; i < 4; ++i) {
                        float xs = xv[i][k];
                        accL[i] += xs * wl4;
                        accR[i] += xs * wr4;
                    }
                }
            }
        }
        #pragma unroll
        for (int i = 0; i < 4; ++i) {
            *(f4*)&xl[(size_t)(n0 + i) * FDIM + c0] = accL[i];
            *(f4*)&xr[(size_t)(n0 + i) * FDIM + c0] = accR[i];
        }
    } else {
        for (int i = 0; i < 4; ++i) {
            int n = n0 + i;
            if (n >= N) break;
            f4 aL = bLv;
            f4 aR = bRv;
            for (int k = 0; k < DIN; ++k) {
                float xs = xin[(size_t)n * DIN + k];
                f4 wl4 = *(const f4*)&Wl[k * FDIM + c0];
                f4 wr4 = *(const f4*)&Wr[k * FDIM + c0];
                aL += xs * wl4;
                aR += xs * wr4;
            }
            *(f4*)&xl[(size_t)n * FDIM + c0] = aL;
            *(f4*)&xr[(size_t)n * FDIM + c0] = aR;
        }
    }
}

// ---------------------------------------------------------------------------
// Merged GATv2 layer: one wave per destination node; DPP score reduction;
// edges processed in PAIRS (two independent score chains, one rescale).
__global__ __launch_bounds__(256) void gat_layer_kernel(
    const float* __restrict__ xl, const float* __restrict__ xr,
    const float* __restrict__ att, const float* __restrict__ bias,
    const int* __restrict__ rowptr, const int* __restrict__ srcs,
    float* __restrict__ xout,                       // [N,48] (non-final)
    float* __restrict__ out,                        // [N]    (final)
    const float* __restrict__ head_w, const float* __restrict__ head_b,
    int N, int final_flag) {
    int wave = (int)((blockIdx.x * blockDim.x + threadIdx.x) >> 6);
    int lane = (int)(threadIdx.x & 63);
    if (wave >= N) return;
    int n  = wave;
    int h  = lane >> 4;
    int cl = lane & 15;
    int j0 = h * HID + cl;          // flat index into [4*48]

    float a0 = att[j0], a1 = att[j0 + 16], a2 = att[j0 + 32];
    const float* xrp = xr + (size_t)n * FDIM;
    float r0 = xrp[j0], r1 = xrp[j0 + 16], r2 = xrp[j0 + 32];

    float m = -INFINITY, denom = 0.f;
    float acc0 = 0.f, acc1 = 0.f, acc2 = 0.f;

    int e0 = rowptr[n], e1 = rowptr[n + 1];
    int e = e0;
    // pair loop
    for (; e + 1 < e1; e += 2) {
        int sa = srcs[e], sb = srcs[e + 1];
        const float* xa = xl + (size_t)sa * FDIM;
        const float* xb = xl + (size_t)sb * FDIM;
        float al0 = xa[j0], al1 = xa[j0 + 16], al2 = xa[j0 + 32];
        float bl0 = xb[j0], bl1 = xb[j0 + 16], bl2 = xb[j0 + 32];

        float ta0 = al0 + r0; ta0 = (ta0 > 0.f) ? ta0 : NEG_SLOPE * ta0;
        float ta1 = al1 + r1; ta1 = (ta1 > 0.f) ? ta1 : NEG_SLOPE * ta1;
        float ta2 = al2 + r2; ta2 = (ta2 > 0.f) ? ta2 : NEG_SLOPE * ta2;
        float tb0 = bl0 + r0; tb0 = (tb0 > 0.f) ? tb0 : NEG_SLOPE * tb0;
        float tb1 = bl1 + r1; tb1 = (tb1 > 0.f) ? tb1 : NEG_SLOPE * tb1;
        float tb2 = bl2 + r2; tb2 = (tb2 > 0.f) ? tb2 : NEG_SLOPE * tb2;
        float sA = red16(ta0 * a0 + ta1 * a1 + ta2 * a2);
        float sB = red16(tb0 * a0 + tb1 * a1 + tb2 * a2);

        float nm    = fmaxf(m, fmaxf(sA, sB));
        float scale = __expf(m - nm);     // m=-inf first iter -> 0
        float pa    = __expf(sA - nm);
        float pb    = __expf(sB - nm);
        denom = denom * scale + pa + pb;
        acc0  = acc0 * scale + pa * al0 + pb * bl0;
        acc1  = acc1 * scale + pa * al1 + pb * bl1;
        acc2  = acc2 * scale + pa * al2 + pb * bl2;
        m = nm;
    }
    // tail edge
    if (e < e1) {
        int s = srcs[e];
        const float* xa = xl + (size_t)s * FDIM;
        float l0 = xa[j0], l1 = xa[j0 + 16], l2 = xa[j0 + 32];
        float t0 = l0 + r0; t0 = (t0 > 0.f) ? t0 : NEG_SLOPE * t0;
        float t1 = l1 + r1; t1 = (t1 > 0.f) ? t1 : NEG_SLOPE * t1;
        float t2 = l2 + r2; t2 = (t2 > 0.f) ? t2 : NEG_SLOPE * t2;
        float sA = red16(t0 * a0 + t1 * a1 + t2 * a2);
        float nm    = fmaxf(m, sA);
        float scale = __expf(m - nm);
        float p     = __expf(sA - nm);
        denom = denom * scale + p;
        acc0  = acc0 * scale + p * l0;
        acc1  = acc1 * scale + p * l1;
        acc2  = acc2 * scale + p * l2;
        m = nm;
    }

    float inv = 1.0f / (denom + 1e-16f);
    float o0 = acc0 * inv, o1 = acc1 * inv, o2 = acc2 * inv;
    // mean over heads: sum across the 4 head groups (once per wave; shfl ok)
    o0 += __shfl_xor(o0, 16); o0 += __shfl_xor(o0, 32);
    o1 += __shfl_xor(o1, 16); o1 += __shfl_xor(o1, 32);
    o2 += __shfl_xor(o2, 16); o2 += __shfl_xor(o2, 32);
    o0 = 0.25f * o0 + bias[cl];
    o1 = 0.25f * o1 + bias[cl + 16];
    o2 = 0.25f * o2 + bias[cl + 32];
    o0 = (o0 > 0.f) ? o0 : expm1f(o0);
    o1 = (o1 > 0.f) ? o1 : expm1f(o1);
    o2 = (o2 > 0.f) ? o2 : expm1f(o2);

    if (!final_flag) {
        if (h == 0) {
            float* xo = xout + (size_t)n * HID;
            xo[cl] = o0; xo[cl + 16] = o1; xo[cl + 32] = o2;
        }
    } else {
        float part = o0 * head_w[cl] + o1 * head_w[cl + 16] + o2 * head_w[cl + 32];
        part = red16(part);
        if (lane == 0) {
            float v = part + head_b[0];
            out[n] = (v > 0.f) ? v : 0.f;
        }
    }
}

// ---------------------------------------------------------------------------
extern "C" void kernel_launch(void* const* d_in, const int* in_sizes, int n_in,
                              void* d_out, int out_size, void* d_ws, size_t ws_size,
                              hipStream_t stream) {
    const float* x0 = (const float*)d_in[0];
    const int*   ei = (const int*)d_in[1];

    const int N  = in_sizes[0] / 3;        // 50000
    const int E  = in_sizes[1] / 2;        // 800000
    const int E2 = E + N;                  // edges incl. self-loops

    const float* Wl[3];  const float* bl[3];
    const float* Wr[3];  const float* br[3];
    const float* att[3]; const float* bias[3];
    for (int li = 0; li < 3; ++li) {
        int b = 2 + 6 * li;
        Wl[li]   = (const float*)d_in[b + 0];
        bl[li]   = (const float*)d_in[b + 1];
        Wr[li]   = (const float*)d_in[b + 2];
        br[li]   = (const float*)d_in[b + 3];
        att[li]  = (const float*)d_in[b + 4];
        bias[li] = (const float*)d_in[b + 5];
    }
    const float* head_w = (const float*)d_in[20];
    const float* head_b = (const float*)d_in[21];
    float* out = (float*)d_out;

    // ---- workspace carve-up (256B aligned) ----
    size_t off = 0;
    auto alloc = [&](size_t bytes) -> void* {
        void* p = (char*)d_ws + off;
        off = (off + bytes + 255) & ~(size_t)255;
        return p;
    };
    const int nb = (N + 255) / 256;
    int*   flag   = (int*)alloc(sizeof(int));
    int*   deg    = (int*)alloc((size_t)N * sizeof(int));        // reused as cursor
    int*   incl   = (int*)alloc((size_t)N * sizeof(int));
    int*   bsum   = (int*)alloc((size_t)nb * sizeof(int));
    int*   rowptr = (int*)alloc((size_t)(N + 1) * sizeof(int));
    int*   srcs   = (int*)alloc((size_t)E2 * sizeof(int));
    float* xlb    = (float*)alloc((size_t)N * FDIM * sizeof(float));
    float* xrb    = (float*)alloc((size_t)N * FDIM * sizeof(float));
    float* xbuf   = (float*)alloc((size_t)N * HID * sizeof(float));
    (void)ws_size;

    // ---- build CSR (layer-invariant) ----
    detect_kernel<<<1, 64, 0, stream>>>(ei, flag);
    (void)hipMemsetAsync(deg, 0, (size_t)N * sizeof(int), stream);
    hist_kernel<<<2048, 256, 0, stream>>>(ei, flag, deg, E, E2);
    scan_local_kernel<<<nb, 256, 0, stream>>>(deg, incl, bsum, N);
    scan_bsum_kernel<<<1, 256, 0, stream>>>(bsum, nb);
    scan_final_kernel<<<nb, 256, 0, stream>>>(incl, bsum, rowptr, N);
    (void)hipMemsetAsync(deg, 0, (size_t)N * sizeof(int), stream);
    scatter_kernel<<<2048, 256, 0, stream>>>(ei, flag, rowptr, deg, srcs, E, E2);

    const int waves_per_block = 4;  // 256 threads
    int gat_blocks = (N + waves_per_block - 1) / waves_per_block;
    int gemm_blocks = (N + 15) / 16;

    // ---- layer 0 (din=3) ----
    gemm2t_kernel<3><<<gemm_blocks, 192, 0, stream>>>(x0, Wl[0], bl[0], Wr[0], br[0], xlb, xrb, N);
    gat_layer_kernel<<<gat_blocks, 256, 0, stream>>>(xlb, xrb, att[0], bias[0],
        rowptr, srcs, xbuf, nullptr, nullptr, nullptr, N, 0);

    // ---- layer 1 (din=48) ----
    gemm2t_kernel<HID><<<gemm_blocks, 192, 0, stream>>>(xbuf, Wl[1], bl[1], Wr[1], br[1], xlb, xrb, N);
    gat_layer_kernel<<<gat_blocks, 256, 0, stream>>>(xlb, xrb, att[1], bias[1],
        rowptr, srcs, xbuf, nullptr, nullptr, nullptr, N, 0);

    // ---- layer 2 (din=48) + fused head MLP + ReLU ----
    gemm2t_kernel<HID><<<gemm_blocks, 192, 0, stream>>>(xbuf, Wl[2], bl[2], Wr[2], br[2], xlb, xrb, N);
    gat_layer_kernel<<<gat_blocks, 256, 0, stream>>>(xlb, xrb, att[2], bias[2],
        rowptr, srcs, nullptr, out, head_w, head_b, N, 1);

    (void)n_in; (void)out_size;
}

// Round 5
// 479.988 us; speedup vs baseline: 1.7271x; 1.0358x over previous
//
#include <hip/hip_runtime.h>
#include <hip/hip_bf16.h>
#include <math.h>

#define HEADS 4
#define HID 48
#define FDIM 192   // HEADS*HID
#define NEG_SLOPE 0.2f

typedef float f4 __attribute__((ext_vector_type(4)));

// ---------------------------------------------------------------------------
// DPP helpers: 16-lane sum reduction entirely on the VALU pipe.
template<int CTRL>
__device__ __forceinline__ float dpp_add(float v) {
    int t = __builtin_amdgcn_update_dpp(0, __float_as_int(v), CTRL, 0xF, 0xF, true);
    return v + __int_as_float(t);
}
__device__ __forceinline__ float red16(float v) {
    v = dpp_add<0xB1>(v);    // quad_perm xor1
    v = dpp_add<0x4E>(v);    // quad_perm xor2
    v = dpp_add<0x124>(v);   // row_ror:4
    v = dpp_add<0x128>(v);   // row_ror:8
    return v;   // all 16 lanes of the row-group hold the full sum
}

// Per-wave int64-vs-int32 detection: odd 32-bit words of first 64 entries all
// zero -> int64. Deterministic, identical in every wave.
__device__ __forceinline__ int detect64(const int* __restrict__ ei) {
    int l = (int)(threadIdx.x & 63);
    int v = ei[2 * l + 1];
    return (__ballot(v != 0) == 0ULL) ? 1 : 0;
}

// ---------------------------------------------------------------------------
// Histogram of destination nodes (including self-loops e in [E, E+N)).
__global__ void hist_kernel(const int* __restrict__ ei,
                            int* __restrict__ deg, int E, int E2) {
    int is64 = detect64(ei);
    for (int e = blockIdx.x * blockDim.x + threadIdx.x; e < E2;
         e += gridDim.x * blockDim.x) {
        int d;
        if (e < E) d = is64 ? ei[2 * (E + e)] : ei[E + e];
        else       d = e - E;
        atomicAdd(&deg[d], 1);
    }
}

// ---------------------------------------------------------------------------
// Hierarchical scan: (A) per-block inclusive scan + block sums,
// (B) single-block exclusive scan of block sums, (C) add offsets -> rowptr
//     (also zeroes the scatter cursor, saving a memset dispatch).
__global__ void scan_local_kernel(const int* __restrict__ deg, int* __restrict__ incl,
                                  int* __restrict__ bsum, int N) {
    __shared__ int sm[256];
    int i = blockIdx.x * 256 + threadIdx.x;
    int v = (i < N) ? deg[i] : 0;
    sm[threadIdx.x] = v;
    __syncthreads();
    #pragma unroll
    for (int off = 1; off < 256; off <<= 1) {
        int t = ((int)threadIdx.x >= off) ? sm[threadIdx.x - off] : 0;
        __syncthreads();
        sm[threadIdx.x] += t;
        __syncthreads();
    }
    if (i < N) incl[i] = sm[threadIdx.x];
    if (threadIdx.x == 255) bsum[blockIdx.x] = sm[255];
}

__global__ void scan_bsum_kernel(int* __restrict__ bsum, int nb) {
    __shared__ int sm[256];
    __shared__ int running;
    if (threadIdx.x == 0) running = 0;
    __syncthreads();
    for (int base = 0; base < nb; base += 256) {
        int i = base + (int)threadIdx.x;
        int v = (i < nb) ? bsum[i] : 0;
        sm[threadIdx.x] = v;
        __syncthreads();
        #pragma unroll
        for (int off = 1; off < 256; off <<= 1) {
            int t = ((int)threadIdx.x >= off) ? sm[threadIdx.x - off] : 0;
            __syncthreads();
            sm[threadIdx.x] += t;
            __syncthreads();
        }
        if (i < nb) bsum[i] = running + sm[threadIdx.x] - v;   // exclusive
        __syncthreads();
        if (threadIdx.x == 0) running += sm[255];
        __syncthreads();
    }
}

__global__ void scan_final_kernel(const int* __restrict__ incl, const int* __restrict__ bsum,
                                  int* __restrict__ rowptr, int* __restrict__ cursor, int N) {
    int i = blockIdx.x * 256 + threadIdx.x;
    if (i < N) { rowptr[i + 1] = incl[i] + bsum[blockIdx.x]; cursor[i] = 0; }
    if (i == 0) rowptr[0] = 0;
}

// ---------------------------------------------------------------------------
// Scatter edges into CSR order (sorted by dst). cursor zeroed by scan_final.
__global__ void scatter_kernel(const int* __restrict__ ei,
                               const int* __restrict__ rowptr, int* __restrict__ cursor,
                               int* __restrict__ srcs, int E, int E2) {
    int is64 = detect64(ei);
    for (int e = blockIdx.x * blockDim.x + threadIdx.x; e < E2;
         e += gridDim.x * blockDim.x) {
        int s, d;
        if (e < E) {
            if (is64) { s = ei[2 * e]; d = ei[2 * (E + e)]; }
            else      { s = ei[e];     d = ei[E + e]; }
        } else {
            s = d = e - E;
        }
        int pos = rowptr[d] + atomicAdd(&cursor[d], 1);
        srcs[pos] = s;
    }
}

// ---------------------------------------------------------------------------
// Dual GEMM, register-tiled: xl = xin@Wl + bl, xr = xin@Wr + br.
template<int DIN>
__global__ __launch_bounds__(192) void gemm2t_kernel(
    const float* __restrict__ xin,
    const float* __restrict__ Wl, const float* __restrict__ bl,
    const float* __restrict__ Wr, const float* __restrict__ br,
    float* __restrict__ xl, float* __restrict__ xr, int N) {
    int t  = (int)threadIdx.x;
    int cg = t % 48;           // column group -> cols c0..c0+3
    int ng = t / 48;           // node group 0..3
    int c0 = cg * 4;
    int n0 = blockIdx.x * 16 + ng * 4;
    if (n0 >= N) return;

    f4 bLv = *(const f4*)&bl[c0];
    f4 bRv = *(const f4*)&br[c0];
    f4 accL[4], accR[4];
    #pragma unroll
    for (int i = 0; i < 4; ++i) { accL[i] = bLv; accR[i] = bRv; }

    if (n0 + 3 < N) {
        if (DIN == 3) {
            float xv[4][3];
            #pragma unroll
            for (int i = 0; i < 4; ++i) {
                const float* xp = xin + (size_t)(n0 + i) * 3;
                xv[i][0] = xp[0]; xv[i][1] = xp[1]; xv[i][2] = xp[2];
            }
            #pragma unroll
            for (int k = 0; k < 3; ++k) {
                f4 wl4 = *(const f4*)&Wl[k * FDIM + c0];
                f4 wr4 = *(const f4*)&Wr[k * FDIM + c0];
                #pragma unroll
                for (int i = 0; i < 4; ++i) {
                    float xs = xv[i][k];
                    accL[i] += xs * wl4;
                    accR[i] += xs * wr4;
                }
            }
        } else {
            #pragma unroll
            for (int kk = 0; kk < DIN; kk += 8) {
                float xv[4][8];
                #pragma unroll
                for (int i = 0; i < 4; ++i) {
                    const float* xp = xin + (size_t)(n0 + i) * DIN + kk;
                    f4 xa = *(const f4*)xp;
                    f4 xb = *(const f4*)(xp + 4);
                    #pragma unroll
                    for (int q = 0; q < 4; ++q) { xv[i][q] = xa[q]; xv[i][4 + q] = xb[q]; }
                }
                #pragma unroll
                for (int k = 0; k < 8; ++k) {
                    f4 wl4 = *(const f4*)&Wl[(kk + k) * FDIM + c0];
                    f4 wr4 = *(const f4*)&Wr[(kk + k) * FDIM + c0];
                    #pragma unroll
                    for (int i = 0; i < 4; ++i) {
                        float xs = xv[i][k];
                        accL[i] += xs * wl4;
                        accR[i] += xs * wr4;
                    }
                }
            }
        }
        #pragma unroll
        for (int i = 0; i < 4; ++i) {
            *(f4*)&xl[(size_t)(n0 + i) * FDIM + c0] = accL[i];
            *(f4*)&xr[(size_t)(n0 + i) * FDIM + c0] = accR[i];
        }
    } else {
        for (int i = 0; i < 4; ++i) {
            int n = n0 + i;
            if (n >= N) break;
            f4 aL = bLv;
            f4 aR = bRv;
            for (int k = 0; k < DIN; ++k) {
                float xs = xin[(size_t)n * DIN + k];
                f4 wl4 = *(const f4*)&Wl[k * FDIM + c0];
                f4 wr4 = *(const f4*)&Wr[k * FDIM + c0];
                aL += xs * wl4;
                aR += xs * wr4;
            }
            *(f4*)&xl[(size_t)n * FDIM + c0] = aL;
            *(f4*)&xr[(size_t)n * FDIM + c0] = aR;
        }
    }
}

// ---------------------------------------------------------------------------
// Merged GATv2 layer: one wave per destination node.
// 4-edge batches with clamped indices; defer-max softmax (T13, THR=8):
// rescale only when a batch max exceeds m+8 (wave-uniform __any branch,
// ~once per node). Steady state per edge: gather + lrelu-dot + red16 +
// exp + independent FMAs -> software-pipelines.
#define SCORE_MASKED (-1e38f)
#define M_INIT       (-3e38f)
#define DEFER_THR    8.0f

__global__ __launch_bounds__(256) void gat_layer_kernel(
    const float* __restrict__ xl, const float* __restrict__ xr,
    const float* __restrict__ att, const float* __restrict__ bias,
    const int* __restrict__ rowptr, const int* __restrict__ srcs,
    float* __restrict__ xout,                       // [N,48] (non-final)
    float* __restrict__ out,                        // [N]    (final)
    const float* __restrict__ head_w, const float* __restrict__ head_b,
    int N, int final_flag) {
    int wave = (int)((blockIdx.x * blockDim.x + threadIdx.x) >> 6);
    wave = __builtin_amdgcn_readfirstlane(wave);   // force SGPR: uniform bases
    if (wave >= N) return;
    int lane = (int)(threadIdx.x & 63);
    int n  = wave;
    int h  = lane >> 4;
    int cl = lane & 15;
    int j0 = h * HID + cl;          // flat index into [4*48]

    float a0 = att[j0], a1 = att[j0 + 16], a2 = att[j0 + 32];
    const float* xrp = xr + (size_t)n * FDIM;
    float r0 = xrp[j0], r1 = xrp[j0 + 16], r2 = xrp[j0 + 32];

    float m = M_INIT, denom = 0.f;
    float acc0 = 0.f, acc1 = 0.f, acc2 = 0.f;

    int e0 = rowptr[n], e1 = rowptr[n + 1];
    int elast = e1 - 1;

    for (int e = e0; e < e1; e += 4) {
        int i0 = e,     i1 = e + 1,  i2 = e + 2,  i3 = e + 3;
        int k0 = (i0 < e1) ? i0 : elast;
        int k1 = (i1 < e1) ? i1 : elast;
        int k2 = (i2 < e1) ? i2 : elast;
        int k3 = (i3 < e1) ? i3 : elast;
        int s0 = srcs[k0], s1 = srcs[k1], s2 = srcs[k2], s3 = srcs[k3];
        const float* p0 = xl + (size_t)s0 * FDIM;   // uniform (SGPR) bases
        const float* p1 = xl + (size_t)s1 * FDIM;
        const float* p2 = xl + (size_t)s2 * FDIM;
        const float* p3 = xl + (size_t)s3 * FDIM;
        float l00 = p0[j0], l01 = p0[j0 + 16], l02 = p0[j0 + 32];
        float l10 = p1[j0], l11 = p1[j0 + 16], l12 = p1[j0 + 32];
        float l20 = p2[j0], l21 = p2[j0 + 16], l22 = p2[j0 + 32];
        float l30 = p3[j0], l31 = p3[j0 + 16], l32 = p3[j0 + 32];

        #define LRELU(x) (fmaf(NEG_SLOPE, fminf((x), 0.f), fmaxf((x), 0.f)))
        float sc0 = LRELU(l00 + r0) * a0 + LRELU(l01 + r1) * a1 + LRELU(l02 + r2) * a2;
        float sc1 = LRELU(l10 + r0) * a0 + LRELU(l11 + r1) * a1 + LRELU(l12 + r2) * a2;
        float sc2 = LRELU(l20 + r0) * a0 + LRELU(l21 + r1) * a1 + LRELU(l22 + r2) * a2;
        float sc3 = LRELU(l30 + r0) * a0 + LRELU(l31 + r1) * a1 + LRELU(l32 + r2) * a2;
        #undef LRELU
        sc0 = red16(sc0); sc1 = red16(sc1); sc2 = red16(sc2); sc3 = red16(sc3);
        sc0 = (i0 < e1) ? sc0 : SCORE_MASKED;
        sc1 = (i1 < e1) ? sc1 : SCORE_MASKED;
        sc2 = (i2 < e1) ? sc2 : SCORE_MASKED;
        sc3 = (i3 < e1) ? sc3 : SCORE_MASKED;

        float bmax = fmaxf(fmaxf(sc0, sc1), fmaxf(sc2, sc3));
        if (__any(bmax > m + DEFER_THR)) {          // rare after first batch
            float nm = fmaxf(m, bmax);
            float sc = __expf(m - nm);              // m=M_INIT -> 0
            denom *= sc; acc0 *= sc; acc1 *= sc; acc2 *= sc;
            m = nm;
        }
        float q0 = __expf(sc0 - m);
        float q1 = __expf(sc1 - m);
        float q2 = __expf(sc2 - m);
        float q3 = __expf(sc3 - m);
        denom += (q0 + q1) + (q2 + q3);
        acc0 = fmaf(q0, l00, fmaf(q1, l10, fmaf(q2, l20, fmaf(q3, l30, acc0))));
        acc1 = fmaf(q0, l01, fmaf(q1, l11, fmaf(q2, l21, fmaf(q3, l31, acc1))));
        acc2 = fmaf(q0, l02, fmaf(q1, l12, fmaf(q2, l22, fmaf(q3, l32, acc2))));
    }

    float inv = 1.0f / (denom + 1e-16f);
    float o0 = acc0 * inv, o1 = acc1 * inv, o2 = acc2 * inv;
    // mean over heads: sum across the 4 head groups
    o0 += __shfl_xor(o0, 16); o0 += __shfl_xor(o0, 32);
    o1 += __shfl_xor(o1, 16); o1 += __shfl_xor(o1, 32);
    o2 += __shfl_xor(o2, 16); o2 += __shfl_xor(o2, 32);
    o0 = 0.25f * o0 + bias[cl];
    o1 = 0.25f * o1 + bias[cl + 16];
    o2 = 0.25f * o2 + bias[cl + 32];
    o0 = (o0 > 0.f) ? o0 : expm1f(o0);
    o1 = (o1 > 0.f) ? o1 : expm1f(o1);
    o2 = (o2 > 0.f) ? o2 : expm1f(o2);

    if (!final_flag) {
        if (h == 0) {
            float* xo = xout + (size_t)n * HID;
            xo[cl] = o0; xo[cl + 16] = o1; xo[cl + 32] = o2;
        }
    } else {
        float part = o0 * head_w[cl] + o1 * head_w[cl + 16] + o2 * head_w[cl + 32];
        part = red16(part);
        if (lane == 0) {
            float v = part + head_b[0];
            out[n] = (v > 0.f) ? v : 0.f;
        }
    }
}

// ---------------------------------------------------------------------------
extern "C" void kernel_launch(void* const* d_in, const int* in_sizes, int n_in,
                              void* d_out, int out_size, void* d_ws, size_t ws_size,
                              hipStream_t stream) {
    const float* x0 = (const float*)d_in[0];
    const int*   ei = (const int*)d_in[1];

    const int N  = in_sizes[0] / 3;        // 50000
    const int E  = in_sizes[1] / 2;        // 800000
    const int E2 = E + N;                  // edges incl. self-loops

    const float* Wl[3];  const float* bl[3];
    const float* Wr[3];  const float* br[3];
    const float* att[3]; const float* bias[3];
    for (int li = 0; li < 3; ++li) {
        int b = 2 + 6 * li;
        Wl[li]   = (const float*)d_in[b + 0];
        bl[li]   = (const float*)d_in[b + 1];
        Wr[li]   = (const float*)d_in[b + 2];
        br[li]   = (const float*)d_in[b + 3];
        att[li]  = (const float*)d_in[b + 4];
        bias[li] = (const float*)d_in[b + 5];
    }
    const float* head_w = (const float*)d_in[20];
    const float* head_b = (const float*)d_in[21];
    float* out = (float*)d_out;

    // ---- workspace carve-up (256B aligned) ----
    size_t off = 0;
    auto alloc = [&](size_t bytes) -> void* {
        void* p = (char*)d_ws + off;
        off = (off + bytes + 255) & ~(size_t)255;
        return p;
    };
    const int nb = (N + 255) / 256;
    int*   deg    = (int*)alloc((size_t)N * sizeof(int));        // reused as cursor
    int*   incl   = (int*)alloc((size_t)N * sizeof(int));
    int*   bsum   = (int*)alloc((size_t)nb * sizeof(int));
    int*   rowptr = (int*)alloc((size_t)(N + 1) * sizeof(int));
    int*   srcs   = (int*)alloc((size_t)E2 * sizeof(int));
    float* xlb    = (float*)alloc((size_t)N * FDIM * sizeof(float));
    float* xrb    = (float*)alloc((size_t)N * FDIM * sizeof(float));
    float* xbuf   = (float*)alloc((size_t)N * HID * sizeof(float));
    (void)ws_size;

    // ---- build CSR (layer-invariant) ----
    (void)hipMemsetAsync(deg, 0, (size_t)N * sizeof(int), stream);
    hist_kernel<<<2048, 256, 0, stream>>>(ei, deg, E, E2);
    scan_local_kernel<<<nb, 256, 0, stream>>>(deg, incl, bsum, N);
    scan_bsum_kernel<<<1, 256, 0, stream>>>(bsum, nb);
    scan_final_kernel<<<nb, 256, 0, stream>>>(incl, bsum, rowptr, deg, N);
    scatter_kernel<<<2048, 256, 0, stream>>>(ei, rowptr, deg, srcs, E, E2);

    const int waves_per_block = 4;  // 256 threads
    int gat_blocks = (N + waves_per_block - 1) / waves_per_block;
    int gemm_blocks = (N + 15) / 16;

    // ---- layer 0 (din=3) ----
    gemm2t_kernel<3><<<gemm_blocks, 192, 0, stream>>>(x0, Wl[0], bl[0], Wr[0], br[0], xlb, xrb, N);
    gat_layer_kernel<<<gat_blocks, 256, 0, stream>>>(xlb, xrb, att[0], bias[0],
        rowptr, srcs, xbuf, nullptr, nullptr, nullptr, N, 0);

    // ---- layer 1 (din=48) ----
    gemm2t_kernel<HID><<<gemm_blocks, 192, 0, stream>>>(xbuf, Wl[1], bl[1], Wr[1], br[1], xlb, xrb, N);
    gat_layer_kernel<<<gat_blocks, 256, 0, stream>>>(xlb, xrb, att[1], bias[1],
        rowptr, srcs, xbuf, nullptr, nullptr, nullptr, N, 0);

    // ---- layer 2 (din=48) + fused head MLP + ReLU ----
    gemm2t_kernel<HID><<<gemm_blocks, 192, 0, stream>>>(xbuf, Wl[2], bl[2], Wr[2], br[2], xlb, xrb, N);
    gat_layer_kernel<<<gat_blocks, 256, 0, stream>>>(xlb, xrb, att[2], bias[2],
        rowptr, srcs, nullptr, out, head_w, head_b, N, 1);

    (void)n_in; (void)out_size;
}